// Round 3
// baseline (89.608 us; speedup 1.0000x reference)
//
#include <hip/hip_runtime.h>
#include <hip/hip_cooperative_groups.h>
#include <math.h>

// QuGCN chain-product kernel, round 3.
// chain = v_0 * (prod_i <v_i, v_{i+1}>) * v_{E-1}^dag  with v_i = U f_i/|f_i|.
// NEW: U is unitary => U^dag U = I => c_i = <v_i,v_{i+1}> = f_i.f_{i+1}/(|f_i||f_{i+1}|)
// is REAL and independent of U. Per item: 4-elem dot + shared norms; per THREAD:
// one frexp+logf of the double-accumulated ratio prod, plus a negative-dot count
// (phase = pi*count). U only appears in the tiny finalize (v0, v_{E-1}).
// |c_i|<=1 so the f32 reference chain underflows to exactly 0; gate s=0 when
// sum(log|c|) < -85.
// Single cooperative launch (grid.sync) fuses partial-reduce + finalize; falls
// back to 2 kernels if hipLaunchCooperativeKernel is refused.

namespace cg = cooperative_groups;

#define W_MUL 0.63245553203367586640f  // sqrt(2/5)
#define LN2   0.69314718055994530942
#define TPB   256
#define KIT   4

struct C { float re, im; };
__device__ __forceinline__ C cmul(C a, C b) {
    return { a.re * b.re - a.im * b.im, a.re * b.im + a.im * b.re };
}
__device__ __forceinline__ C cadd(C a, C b) { return { a.re + b.re, a.im + b.im }; }

__device__ __forceinline__ void build_U(const float* __restrict__ w, C U[4][4]) {
    float h0 = w[0] * W_MUL * 0.5f, h1 = w[1] * W_MUL * 0.5f, h2 = w[2] * W_MUL * 0.5f;
    float c0 = cosf(h0), s0 = sinf(h0);
    float c1 = cosf(h1), s1 = sinf(h1);
    float c2 = cosf(h2), s2 = sinf(h2);
    C rx[2][2] = { { {c0, 0.f}, {0.f, -s0} }, { {0.f, -s0}, {c0, 0.f} } };
    C ry[2][2] = { { {c1, 0.f}, {-s1, 0.f} }, { {s1, 0.f}, {c1, 0.f} } };
    C rz[2][2] = { { {c2, -s2}, {0.f, 0.f} }, { {0.f, 0.f}, {c2, s2} } };
    C t[2][2], u[2][2];
    for (int i = 0; i < 2; i++)
        for (int j = 0; j < 2; j++) {
            C a = {0.f, 0.f};
            for (int k = 0; k < 2; k++) a = cadd(a, cmul(ry[i][k], rx[k][j]));
            t[i][j] = a;
        }
    for (int i = 0; i < 2; i++)
        for (int j = 0; j < 2; j++) {
            C a = {0.f, 0.f};
            for (int k = 0; k < 2; k++) a = cadd(a, cmul(rz[i][k], t[k][j]));
            u[i][j] = a;
        }
    for (int a = 0; a < 2; a++)
        for (int b = 0; b < 2; b++)
            for (int c = 0; c < 2; c++)
                for (int d = 0; d < 2; d++)
                    U[2 * a + c][2 * b + d] = cmul(u[a][b], u[c][d]);
}

__device__ __forceinline__ void edge_v2(float2 fa, float2 fb, const C U[4][4], C v[4]) {
    float f[4] = { fa.x, fa.y, fb.x, fb.y };
    float n2 = f[0] * f[0] + f[1] * f[1] + f[2] * f[2] + f[3] * f[3];
    float inv = rsqrtf(n2);
    #pragma unroll
    for (int k = 0; k < 4; k++) {
        float re = 0.f, im = 0.f;
        #pragma unroll
        for (int j = 0; j < 4; j++) {
            re += U[k][j].re * f[j];
            im += U[k][j].im * f[j];
        }
        v[k] = { re * inv, im * inv };
    }
}

// ---- phase 1: per-thread KIT consecutive items -> per-block partial ----
__device__ __forceinline__ void phase1(const int* __restrict__ edges,
                                       const float2* __restrict__ nf,
                                       int nitems, double* __restrict__ pL,
                                       int* __restrict__ pC) {
    int tid = blockIdx.x * TPB + threadIdx.x;
    int base = tid * KIT;
    double lsum = 0.0;
    int neg = 0;

    if (base < nitems) {
        int cnt = min(KIT, nitems - base);
        int ia[KIT + 1], ib[KIT + 1];
        if (cnt == KIT) {
            const int4* e4 = (const int4*)(edges + 2 * base);  // 32B aligned
            int4 p0 = e4[0], p1 = e4[1];
            int2 p2 = *(const int2*)(edges + 2 * base + 8);
            ia[0] = p0.x; ib[0] = p0.y; ia[1] = p0.z; ib[1] = p0.w;
            ia[2] = p1.x; ib[2] = p1.y; ia[3] = p1.z; ib[3] = p1.w;
            ia[4] = p2.x; ib[4] = p2.y;
        } else {
            #pragma unroll
            for (int e = 0; e <= KIT; e++) {
                if (e <= cnt) { ia[e] = edges[2 * (base + e)]; ib[e] = edges[2 * (base + e) + 1]; }
                else          { ia[e] = 0; ib[e] = 0; }
            }
        }
        float2 ga[KIT + 1], gb[KIT + 1];
        #pragma unroll
        for (int e = 0; e <= KIT; e++) { ga[e] = nf[ia[e]]; gb[e] = nf[ib[e]]; }

        float n2[KIT + 1];
        #pragma unroll
        for (int e = 0; e <= KIT; e++)
            n2[e] = ga[e].x * ga[e].x + ga[e].y * ga[e].y
                  + gb[e].x * gb[e].x + gb[e].y * gb[e].y;

        double num = 1.0, den = 1.0;
        #pragma unroll
        for (int e = 0; e < KIT; e++) {
            if (e >= cnt) break;
            float dot = ga[e].x * ga[e + 1].x + ga[e].y * ga[e + 1].y
                      + gb[e].x * gb[e + 1].x + gb[e].y * gb[e + 1].y;
            num *= (double)(dot * dot);
            den *= (double)(n2[e] * n2[e + 1]);
            neg += (dot < 0.f) ? 1 : 0;
        }
        double Rt = num / den;               // prod of c_i^2 for this thread, in (0,1]
        int ex;
        double mf = frexp(Rt, &ex);          // Rt = mf * 2^ex, mf in [0.5,1)
        lsum = 0.5 * ((double)ex * LN2 + (double)logf((float)mf));  // Rt==0 -> -inf
    }

    for (int off = 32; off; off >>= 1) {
        lsum += __shfl_down(lsum, off, 64);
        neg  += __shfl_down(neg, off, 64);
    }
    __shared__ double sl[TPB / 64];
    __shared__ int    sn[TPB / 64];
    int wid = threadIdx.x >> 6, lid = threadIdx.x & 63;
    if (lid == 0) { sl[wid] = lsum; sn[wid] = neg; }
    __syncthreads();
    if (threadIdx.x == 0) {
        double L = lsum; int N = neg;
        for (int w = 1; w < TPB / 64; w++) { L += sl[w]; N += sn[w]; }
        __hip_atomic_store(&pL[blockIdx.x], L, __ATOMIC_RELEASE, __HIP_MEMORY_SCOPE_AGENT);
        __hip_atomic_store(&pC[blockIdx.x], N, __ATOMIC_RELEASE, __HIP_MEMORY_SCOPE_AGENT);
    }
}

// ---- phase 2: reduce partials, finalize (one block) ----
__device__ __forceinline__ void phase2(const int* __restrict__ edges,
                                       const float2* __restrict__ nf,
                                       const float* __restrict__ weight,
                                       const float* __restrict__ lin_w,
                                       const float* __restrict__ lin_b,
                                       int E, int nparts,
                                       const double* __restrict__ pL,
                                       const int* __restrict__ pC,
                                       float* __restrict__ out) {
    int t = threadIdx.x;
    double L = 0.0; int N = 0;
    for (int i = t; i < nparts; i += TPB) {
        L += __hip_atomic_load(&pL[i], __ATOMIC_ACQUIRE, __HIP_MEMORY_SCOPE_AGENT);
        N += __hip_atomic_load(&pC[i], __ATOMIC_ACQUIRE, __HIP_MEMORY_SCOPE_AGENT);
    }
    for (int off = 32; off; off >>= 1) {
        L += __shfl_down(L, off, 64);
        N += __shfl_down(N, off, 64);
    }
    __shared__ double sl2[TPB / 64];
    __shared__ int    sn2[TPB / 64];
    int wid = t >> 6, lid = t & 63;
    if (lid == 0) { sl2[wid] = L; sn2[wid] = N; }
    __syncthreads();
    if (t != 0) return;
    for (int w = 1; w < TPB / 64; w++) { L += sl2[w]; N += sn2[w]; }

    C U[4][4];
    build_U(weight, U);
    C v0[4], vl[4];
    edge_v2(nf[edges[0]], nf[edges[1]], U, v0);
    edge_v2(nf[edges[2 * (E - 1)]], nf[edges[2 * (E - 1) + 1]], U, vl);

    // s = (+-1)^N * exp(L), real (c_i are real); gate reproduces f32 underflow
    float s_re;
    if (!(L > -85.0)) s_re = 0.f;
    else              s_re = (float)((N & 1) ? -exp(L) : exp(L));

    float x[16];
    for (int a = 0; a < 4; a++)
        for (int d = 0; d < 4; d++)
            x[4 * a + d] = s_re * (v0[a].re * vl[d].re + v0[a].im * vl[d].im);

    float l0 = lin_b[0], l1 = lin_b[1];
    for (int k = 0; k < 16; k++) {
        l0 += x[k] * lin_w[k];
        l1 += x[k] * lin_w[16 + k];
    }
    float mx = fmaxf(l0, l1);
    float e0 = expf(l0 - mx), e1 = expf(l1 - mx);
    float inv = 1.f / (e0 + e1);
    out[0] = e0 * inv;
    out[1] = e1 * inv;
}

// ---- fused cooperative kernel ----
__global__ void __launch_bounds__(TPB)
k_fused(const int* __restrict__ edges, const float2* __restrict__ nf,
        const float* __restrict__ weight, const float* __restrict__ lin_w,
        const float* __restrict__ lin_b, int nitems, int E, int nparts,
        double* __restrict__ pL, int* __restrict__ pC, float* __restrict__ out) {
    phase1(edges, nf, nitems, pL, pC);
    cg::this_grid().sync();
    if (blockIdx.x == 0)
        phase2(edges, nf, weight, lin_w, lin_b, E, nparts, pL, pC, out);
}

// ---- fallback: two plain kernels ----
__global__ void __launch_bounds__(TPB)
k_part(const int* __restrict__ edges, const float2* __restrict__ nf,
       int nitems, double* __restrict__ pL, int* __restrict__ pC) {
    phase1(edges, nf, nitems, pL, pC);
}

__global__ void __launch_bounds__(TPB)
k_fin(const int* __restrict__ edges, const float2* __restrict__ nf,
      const float* __restrict__ weight, const float* __restrict__ lin_w,
      const float* __restrict__ lin_b, int E, int nparts,
      const double* __restrict__ pL, const int* __restrict__ pC,
      float* __restrict__ out) {
    phase2(edges, nf, weight, lin_w, lin_b, E, nparts, pL, pC, out);
}

extern "C" void kernel_launch(void* const* d_in, const int* in_sizes, int n_in,
                              void* d_out, int out_size, void* d_ws, size_t ws_size,
                              hipStream_t stream) {
    const int*    edges  = (const int*)d_in[0];     // [E,2] int32
    const float2* nf     = (const float2*)d_in[1];  // [N,2]
    const float*  weight = (const float*)d_in[2];   // [5]
    const float*  lin_w  = (const float*)d_in[3];   // [2,16]
    const float*  lin_b  = (const float*)d_in[4];   // [2]
    float* out = (float*)d_out;

    int E = in_sizes[0] / 2;
    int nitems = E - 1;

    int per_block = TPB * KIT;
    int blocks = (nitems + per_block - 1) / per_block;  // 512 for E=524288

    double* pL = (double*)d_ws;
    int*    pC = (int*)(pL + blocks);

    void* args[] = { (void*)&edges, (void*)&nf, (void*)&weight, (void*)&lin_w,
                     (void*)&lin_b, (void*)&nitems, (void*)&E, (void*)&blocks,
                     (void*)&pL, (void*)&pC, (void*)&out };
    hipError_t err = hipLaunchCooperativeKernel((void*)k_fused, dim3(blocks),
                                                dim3(TPB), args, 0, stream);
    if (err != hipSuccess) {
        (void)hipGetLastError();  // clear sticky error, use plain 2-kernel path
        k_part<<<blocks, TPB, 0, stream>>>(edges, nf, nitems, pL, pC);
        k_fin<<<1, TPB, 0, stream>>>(edges, nf, weight, lin_w, lin_b,
                                     E, blocks, pL, pC, out);
    }
}

// Round 4
// 15.775 us; speedup vs baseline: 5.6805x; 5.6805x over previous
//
#include <hip/hip_runtime.h>
#include <math.h>

// QuGCN chain-product kernel, round 4.
// chain = v_0 * (prod_i c_i) * v_{E-1}^dag,  v_i = U f_i/|f_i|.
// U unitary => c_i = f_i.f_{i+1}/(|f_i||f_{i+1}|)  (REAL, U-independent).
// Per thread (KIT=2 items): gather own 2 f-vectors; neighbor f + norm via
// __shfl_down(1) (lane 63 loads directly). Accumulate prod(c_i^2) as
// num/den in double, count sign flips; one frexp+logf per thread.
// |c_i|<=1 => f32 reference chain underflows to exactly 0; gate s=0 when
// sum(log|c|) < -85.
// R3 lesson: cg::grid().sync() costs ~60us on MI355X (8 XCDs) — 2 plain
// kernels (R2 skeleton) is far cheaper.

#define W_MUL 0.63245553203367586640f  // sqrt(2/5)
#define LN2   0.69314718055994530942
#define TPB   256

struct C { float re, im; };
__device__ __forceinline__ C cmul(C a, C b) {
    return { a.re * b.re - a.im * b.im, a.re * b.im + a.im * b.re };
}
__device__ __forceinline__ C cadd(C a, C b) { return { a.re + b.re, a.im + b.im }; }

__device__ __forceinline__ void build_U(const float* __restrict__ w, C U[4][4]) {
    float h0 = w[0] * W_MUL * 0.5f, h1 = w[1] * W_MUL * 0.5f, h2 = w[2] * W_MUL * 0.5f;
    float c0 = cosf(h0), s0 = sinf(h0);
    float c1 = cosf(h1), s1 = sinf(h1);
    float c2 = cosf(h2), s2 = sinf(h2);
    C rx[2][2] = { { {c0, 0.f}, {0.f, -s0} }, { {0.f, -s0}, {c0, 0.f} } };
    C ry[2][2] = { { {c1, 0.f}, {-s1, 0.f} }, { {s1, 0.f}, {c1, 0.f} } };
    C rz[2][2] = { { {c2, -s2}, {0.f, 0.f} }, { {0.f, 0.f}, {c2, s2} } };
    C t[2][2], u[2][2];
    for (int i = 0; i < 2; i++)
        for (int j = 0; j < 2; j++) {
            C a = {0.f, 0.f};
            for (int k = 0; k < 2; k++) a = cadd(a, cmul(ry[i][k], rx[k][j]));
            t[i][j] = a;
        }
    for (int i = 0; i < 2; i++)
        for (int j = 0; j < 2; j++) {
            C a = {0.f, 0.f};
            for (int k = 0; k < 2; k++) a = cadd(a, cmul(rz[i][k], t[k][j]));
            u[i][j] = a;
        }
    for (int a = 0; a < 2; a++)
        for (int b = 0; b < 2; b++)
            for (int c = 0; c < 2; c++)
                for (int d = 0; d < 2; d++)
                    U[2 * a + c][2 * b + d] = cmul(u[a][b], u[c][d]);
}

__device__ __forceinline__ void edge_v2(float2 fa, float2 fb, const C U[4][4], C v[4]) {
    float f[4] = { fa.x, fa.y, fb.x, fb.y };
    float n2 = f[0] * f[0] + f[1] * f[1] + f[2] * f[2] + f[3] * f[3];
    float inv = rsqrtf(n2);
    #pragma unroll
    for (int k = 0; k < 4; k++) {
        float re = 0.f, im = 0.f;
        #pragma unroll
        for (int j = 0; j < 4; j++) {
            re += U[k][j].re * f[j];
            im += U[k][j].im * f[j];
        }
        v[k] = { re * inv, im * inv };
    }
}

// phase 1: thread t handles items {2t, 2t+1}; per-block partial (no atomics)
__global__ void __launch_bounds__(TPB)
k_part(const int* __restrict__ edges, const float2* __restrict__ nf,
       int nitems, int E, double* __restrict__ pL, int* __restrict__ pC) {
    int t = blockIdx.x * TPB + threadIdx.x;
    int i0 = 2 * t;                       // first item (= edge-row index)
    int lane = threadIdx.x & 63;
    int Em1 = E - 1;

    double lsum = 0.0;
    int neg = 0;

    if (i0 < nitems + 1 && i0 <= Em1 - 1) {   // rows i0, i0+1 exist
        // own two edge rows: ints [4t .. 4t+3], 16B aligned
        int4 er = *(const int4*)(edges + 4 * t);
        float2 fa0 = nf[er.x], fb0 = nf[er.y];
        float2 fa1 = nf[er.z], fb1 = nf[er.w];
        float n0 = fa0.x * fa0.x + fa0.y * fa0.y + fb0.x * fb0.x + fb0.y * fb0.y;
        float n1 = fa1.x * fa1.x + fa1.y * fa1.y + fb1.x * fb1.x + fb1.y * fb1.y;

        // neighbor row i0+2: from lane+1 via shfl; lane 63 loads directly
        float2 fa2, fb2;
        float n2v;
        fa2.x = __shfl_down(fa0.x, 1, 64);
        fa2.y = __shfl_down(fa0.y, 1, 64);
        fb2.x = __shfl_down(fb0.x, 1, 64);
        fb2.y = __shfl_down(fb0.y, 1, 64);
        n2v   = __shfl_down(n0, 1, 64);
        if (lane == 63) {
            int r2 = (i0 + 2 <= Em1) ? (i0 + 2) : Em1;   // clamp (masked if OOB)
            int2 e2 = *(const int2*)(edges + 2 * r2);
            fa2 = nf[e2.x];
            fb2 = nf[e2.y];
            n2v = fa2.x * fa2.x + fa2.y * fa2.y + fb2.x * fb2.x + fb2.y * fb2.y;
        }

        double num = 1.0, den = 1.0;
        if (i0 < nitems) {          // item i0: c = f_{i0}.f_{i0+1}/(|..||..|)
            float d0 = fa0.x * fa1.x + fa0.y * fa1.y + fb0.x * fb1.x + fb0.y * fb1.y;
            num *= (double)(d0 * d0);
            den *= (double)(n0 * n1);
            neg += (d0 < 0.f) ? 1 : 0;
        }
        if (i0 + 1 < nitems) {      // item i0+1: needs row i0+2
            float d1 = fa1.x * fa2.x + fa1.y * fa2.y + fb1.x * fb2.x + fb1.y * fb2.y;
            num *= (double)(d1 * d1);
            den *= (double)(n1 * n2v);
            neg += (d1 < 0.f) ? 1 : 0;
        }
        double Rt = num / den;          // prod c_i^2, in (0,1]
        int ex;
        double mf = frexp(Rt, &ex);     // Rt = mf*2^ex
        lsum = 0.5 * ((double)ex * LN2 + (double)logf((float)mf)); // Rt==0 -> -inf
    }

    for (int off = 32; off; off >>= 1) {
        lsum += __shfl_down(lsum, off, 64);
        neg  += __shfl_down(neg, off, 64);
    }
    __shared__ double sl[TPB / 64];
    __shared__ int    sn[TPB / 64];
    int wid = threadIdx.x >> 6;
    if (lane == 0) { sl[wid] = lsum; sn[wid] = neg; }
    __syncthreads();
    if (threadIdx.x == 0) {
        double L = lsum; int N = neg;
        for (int w = 1; w < TPB / 64; w++) { L += sl[w]; N += sn[w]; }
        pL[blockIdx.x] = L;
        pC[blockIdx.x] = N;
    }
}

// phase 2: reduce partials, finalize
__global__ void __launch_bounds__(TPB)
k_fin(const int* __restrict__ edges, const float2* __restrict__ nf,
      const float* __restrict__ weight, const float* __restrict__ lin_w,
      const float* __restrict__ lin_b, int E, int nparts,
      const double* __restrict__ pL, const int* __restrict__ pC,
      float* __restrict__ out) {
    int t = threadIdx.x;
    double L = 0.0; int N = 0;
    for (int i = t; i < nparts; i += TPB) { L += pL[i]; N += pC[i]; }
    for (int off = 32; off; off >>= 1) {
        L += __shfl_down(L, off, 64);
        N += __shfl_down(N, off, 64);
    }
    __shared__ double sl2[TPB / 64];
    __shared__ int    sn2[TPB / 64];
    int wid = t >> 6, lane = t & 63;
    if (lane == 0) { sl2[wid] = L; sn2[wid] = N; }
    __syncthreads();
    if (t != 0) return;
    for (int w = 1; w < TPB / 64; w++) { L += sl2[w]; N += sn2[w]; }

    C U[4][4];
    build_U(weight, U);
    C v0[4], vl[4];
    edge_v2(nf[edges[0]], nf[edges[1]], U, v0);
    edge_v2(nf[edges[2 * (E - 1)]], nf[edges[2 * (E - 1) + 1]], U, vl);

    float s_re;
    if (!(L > -85.0)) s_re = 0.f;                      // f32 chain underflowed
    else              s_re = (float)((N & 1) ? -exp(L) : exp(L));

    float x[16];
    for (int a = 0; a < 4; a++)
        for (int d = 0; d < 4; d++)
            x[4 * a + d] = s_re * (v0[a].re * vl[d].re + v0[a].im * vl[d].im);

    float l0 = lin_b[0], l1 = lin_b[1];
    for (int k = 0; k < 16; k++) {
        l0 += x[k] * lin_w[k];
        l1 += x[k] * lin_w[16 + k];
    }
    float mx = fmaxf(l0, l1);
    float e0 = expf(l0 - mx), e1 = expf(l1 - mx);
    float inv = 1.f / (e0 + e1);
    out[0] = e0 * inv;
    out[1] = e1 * inv;
}

extern "C" void kernel_launch(void* const* d_in, const int* in_sizes, int n_in,
                              void* d_out, int out_size, void* d_ws, size_t ws_size,
                              hipStream_t stream) {
    const int*    edges  = (const int*)d_in[0];     // [E,2] int32
    const float2* nf     = (const float2*)d_in[1];  // [N,2]
    const float*  weight = (const float*)d_in[2];   // [5]
    const float*  lin_w  = (const float*)d_in[3];   // [2,16]
    const float*  lin_b  = (const float*)d_in[4];   // [2]
    float* out = (float*)d_out;

    int E = in_sizes[0] / 2;
    int nitems = E - 1;

    int per_block = TPB * 2;
    int blocks = (nitems + per_block - 1) / per_block;  // 1024 for E=524288

    double* pL = (double*)d_ws;
    int*    pC = (int*)(pL + blocks);

    k_part<<<blocks, TPB, 0, stream>>>(edges, nf, nitems, E, pL, pC);
    k_fin<<<1, TPB, 0, stream>>>(edges, nf, weight, lin_w, lin_b,
                                 E, blocks, pL, pC, out);
}